// Round 1
// baseline (240.050 us; speedup 1.0000x reference)
//
#include <hip/hip_runtime.h>

#define Bdim 16
#define Ndim 8192
#define Fdim 256
#define EPS 1e-3f

#define RED_BLOCKS_PER_BATCH 64                    // blocks per batch; block rbi owns rows rbi + 64*k
#define RED_BLOCKS (Bdim * RED_BLOCKS_PER_BATCH)   // 1024 blocks = 4/CU
#define RED_SLOTS 128                              // 8192 / 64 slots per block
#define SLOT_STRIDE_FX4 4096                       // 64 rows * 64 fx4-chunks between slots

#define NORM_BLOCKS 8192
#define TOTAL_CHUNKS (Bdim * Ndim * (Fdim / 4))    // 8388608 float4 chunks

typedef float fx4 __attribute__((ext_vector_type(4)));

// ws layout (floats): [0..255]=sum  [256..511]=sumsq

__global__ __launch_bounds__(512) void init_kernel(float* __restrict__ ws) {
    ws[threadIdx.x] = 0.0f;   // ws is re-poisoned to 0xAA before every timed call
}

// Pass 1: per-feature sum/sumsq over valid rows, AND zero-fill of invalid output
// rows (independent of the statistics). Strided row ownership: block rbi of batch
// b owns rows {rbi + 64*k : k=0..127}. Valid slots are a prefix in k, so every
// block does exactly 128 slots of 1 KB traffic (read if valid, NT-zero if not)
// -> perfectly load-balanced across blocks/CUs, unlike the old contiguous slabs
// where ~half the CUs had no work.
__global__ __launch_bounds__(256) void reduce_kernel(
    const float* __restrict__ x, const int* __restrict__ nv,
    float* __restrict__ ws, float* __restrict__ out)
{
    __shared__ float lds_s[4][Fdim];
    __shared__ float lds_q[4][Fdim];
    const int tid = threadIdx.x;
    const int b   = blockIdx.x >> 6;
    const int rbi = blockIdx.x & 63;
    const int nvb = nv[b];                          // wave-uniform scalar
    // slot k valid iff rbi + 64k < nvb  =>  k < ceil((nvb - rbi)/64); prefix in k
    int kvalid = (nvb - rbi + 63) >> 6;
    kvalid = kvalid < 0 ? 0 : (kvalid > RED_SLOTS ? RED_SLOTS : kvalid);

    const int c = tid & 63;      // float4 chunk within row (wave spans one full row)
    const int r = tid >> 6;      // wave id 0..3: handles slots k = r, r+4, r+8, ...
    const fx4* xb = (const fx4*)(x   + ((size_t)b * Ndim + rbi) * Fdim) + c;
    fx4*       ob = (fx4*)      (out + ((size_t)b * Ndim + rbi) * Fdim) + c;

    float s0=0.f,s1=0.f,s2=0.f,s3=0.f, q0=0.f,q1=0.f,q2=0.f,q3=0.f;

    int k = r;
    // 4 independent 1 KB row-loads in flight per wave — pure streaming
    for (; k + 12 < kvalid; k += 16) {
        const fx4 v0 = xb[(size_t)(k     ) * SLOT_STRIDE_FX4];
        const fx4 v1 = xb[(size_t)(k +  4) * SLOT_STRIDE_FX4];
        const fx4 v2 = xb[(size_t)(k +  8) * SLOT_STRIDE_FX4];
        const fx4 v3 = xb[(size_t)(k + 12) * SLOT_STRIDE_FX4];
        s0 += v0.x; q0 += v0.x*v0.x;  s1 += v0.y; q1 += v0.y*v0.y;
        s2 += v0.z; q2 += v0.z*v0.z;  s3 += v0.w; q3 += v0.w*v0.w;
        s0 += v1.x; q0 += v1.x*v1.x;  s1 += v1.y; q1 += v1.y*v1.y;
        s2 += v1.z; q2 += v1.z*v1.z;  s3 += v1.w; q3 += v1.w*v1.w;
        s0 += v2.x; q0 += v2.x*v2.x;  s1 += v2.y; q1 += v2.y*v2.y;
        s2 += v2.z; q2 += v2.z*v2.z;  s3 += v2.w; q3 += v2.w*v2.w;
        s0 += v3.x; q0 += v3.x*v3.x;  s1 += v3.y; q1 += v3.y*v3.y;
        s2 += v3.z; q2 += v3.z*v3.z;  s3 += v3.w; q3 += v3.w*v3.w;
    }
    for (; k < kvalid; k += 4) {
        const fx4 v = xb[(size_t)k * SLOT_STRIDE_FX4];
        s0 += v.x; q0 += v.x*v.x;  s1 += v.y; q1 += v.y*v.y;
        s2 += v.z; q2 += v.z*v.z;  s3 += v.w; q3 += v.w*v.w;
    }
    // zero-fill this wave's invalid slots (padding rows of out). NT: write-only,
    // keep L2/L3 clean so x stays resident for the norm pass's re-read.
    {
        const fx4 z = {0.f, 0.f, 0.f, 0.f};
        int kz = k;                      // first invalid slot with kz ≡ r (mod 4)
        for (; kz + 12 < RED_SLOTS; kz += 16) {
            __builtin_nontemporal_store(z, ob + (size_t)(kz     ) * SLOT_STRIDE_FX4);
            __builtin_nontemporal_store(z, ob + (size_t)(kz +  4) * SLOT_STRIDE_FX4);
            __builtin_nontemporal_store(z, ob + (size_t)(kz +  8) * SLOT_STRIDE_FX4);
            __builtin_nontemporal_store(z, ob + (size_t)(kz + 12) * SLOT_STRIDE_FX4);
        }
        for (; kz < RED_SLOTS; kz += 4)
            __builtin_nontemporal_store(z, ob + (size_t)kz * SLOT_STRIDE_FX4);
    }

    const int f0 = c * 4;
    lds_s[r][f0+0]=s0; lds_s[r][f0+1]=s1; lds_s[r][f0+2]=s2; lds_s[r][f0+3]=s3;
    lds_q[r][f0+0]=q0; lds_q[r][f0+1]=q1; lds_q[r][f0+2]=q2; lds_q[r][f0+3]=q3;
    __syncthreads();

    float ts = 0.0f, tq = 0.0f;
    #pragma unroll
    for (int rr = 0; rr < 4; rr++) { ts += lds_s[rr][tid]; tq += lds_q[rr][tid]; }
    unsafeAtomicAdd(&ws[tid], ts);          // hw global_atomic_add_f32, device scope
    unsafeAtomicAdd(&ws[Fdim + tid], tq);
}

// Pass 2: normalize VALID rows only (invalid rows were zero-filled in pass 1).
// Finalize fused: each of the 256 threads recomputes its feature's scale/bias
// from the ws sums (L2-hot: 2 KiB per block), stages via LDS.
__global__ __launch_bounds__(256) void norm_kernel(
    const float* __restrict__ x, const int* __restrict__ nv,
    const float* __restrict__ gamma, const float* __restrict__ beta,
    const float* __restrict__ ws, float* __restrict__ out)
{
    __shared__ float s_sc[Fdim], s_bi[Fdim];
    __shared__ int s_nv[Bdim];
    const int tid = threadIdx.x;
    if (tid < Bdim) s_nv[tid] = nv[tid];
    __syncthreads();
    {
        int cnt = 0;
        #pragma unroll
        for (int i = 0; i < Bdim; i++) cnt += s_nv[i];
        const float inv_count = 1.0f / fmaxf((float)cnt, 1.0f);
        const float mean = ws[tid] * inv_count;
        float var = fmaf(ws[Fdim + tid], inv_count, -mean * mean);
        var = fmaxf(var, 0.0f);
        const float s = rsqrtf(var + EPS) * gamma[tid];
        s_sc[tid] = s;
        s_bi[tid] = fmaf(-mean, s, beta[tid]);
    }
    __syncthreads();

    // chunk index c = idx & 63 is loop-invariant (stride % 64 == 0):
    // this thread's 4 scale/bias values live in registers.
    const int c = tid & 63;
    const fx4 sc = ((const fx4*)s_sc)[c];
    const fx4 bi = ((const fx4*)s_bi)[c];

    const int base = blockIdx.x * 256 + tid;
    const int stride = NORM_BLOCKS * 256;                      // 2097152
    #pragma unroll
    for (int it = 0; it < TOTAL_CHUNKS / (NORM_BLOCKS * 256); it++) {  // 4 iters
        const int idx = base + it * stride;
        const int row = idx >> 6;          // 64 chunks per row; wave = one row
        const int b = row >> 13;
        const int n = row & (Ndim - 1);
        if (n < s_nv[b]) {                 // wave-uniform branch; invalid rows: no-op
            const fx4 v = ((const fx4*)x)[idx];   // L3-hot: pass 1 just read it
            fx4 o;
            o.x = fmaf(v.x, sc.x, bi.x);
            o.y = fmaf(v.y, sc.y, bi.y);
            o.z = fmaf(v.z, sc.z, bi.z);
            o.w = fmaf(v.w, sc.w, bi.w);
            __builtin_nontemporal_store(o, (fx4*)out + idx);   // write-only
        }
    }
}

extern "C" void kernel_launch(void* const* d_in, const int* in_sizes, int n_in,
                              void* d_out, int out_size, void* d_ws, size_t ws_size,
                              hipStream_t stream) {
    const float* x     = (const float*)d_in[0];   // f32 [16,8192,256]
    const int*   nv    = (const int*)d_in[1];     // int32 [16]
    const float* gamma = (const float*)d_in[2];   // f32 [256]
    const float* beta  = (const float*)d_in[3];   // f32 [256]
    float* out = (float*)d_out;
    float* ws  = (float*)d_ws;

    init_kernel<<<1, 512, 0, stream>>>(ws);
    reduce_kernel<<<RED_BLOCKS, 256, 0, stream>>>(x, nv, ws, out);
    norm_kernel<<<NORM_BLOCKS, 256, 0, stream>>>(x, nv, gamma, beta, ws, out);
}